// Round 11
// baseline (2977.285 us; speedup 1.0000x reference)
//
#include <hip/hip_runtime.h>

#define N_V  20000
#define B_   8
#define F_   64
#define K_   6
#define OUT_ 64
#define NNZ_ 320000
#define BF   512    // B_*F_
#define NPAIR (N_V / 2)            // 10000 row pairs
#define PCAP 128                   // edge capacity per pair (P(overflow) ~ 1e-40)
#define CHEB_BLOCKS 1024           // 4 blocks/CU needed; capacity 8/CU at <=64 VGPR (2x slack)
#define CHEB_WAVES  (CHEB_BLOCKS * 4)

typedef unsigned short ushort_t;
typedef unsigned int   uint_t;

using frag_ab = __attribute__((ext_vector_type(8))) short;  // 8 bf16 (4 VGPRs)
using frag_cd = __attribute__((ext_vector_type(4))) float;  // 4 f32 acc

// ---- bf16 helpers ----
__device__ __forceinline__ ushort_t f2bf(float f) {          // round-to-nearest-even
    uint_t u = __float_as_uint(f);
    u += 0x7FFFu + ((u >> 16) & 1u);
    return (ushort_t)(u >> 16);
}
__device__ __forceinline__ uint_t pack2(float lo, float hi) {
    return (uint_t)f2bf(lo) | ((uint_t)f2bf(hi) << 16);
}
__device__ __forceinline__ void unpack2(uint_t u, float& lo, float& hi) {
    lo = __uint_as_float(u << 16);
    hi = __uint_as_float(u & 0xFFFF0000u);
}

// ---- hand-rolled grid barrier (monotonic counter, device scope) ----
// All CHEB_BLOCKS blocks are co-resident by construction (see launch config),
// so spinning is deadlock-free. Phase p waits for bar >= p * CHEB_BLOCKS.
__device__ __forceinline__ void gbar(int* __restrict__ bar, int target) {
    __syncthreads();
    if (threadIdx.x == 0) {
        __threadfence();                                   // release prior writes (agent scope)
        __hip_atomic_fetch_add(bar, 1, __ATOMIC_ACQ_REL, __HIP_MEMORY_SCOPE_AGENT);
        while (__hip_atomic_load(bar, __ATOMIC_ACQUIRE, __HIP_MEMORY_SCOPE_AGENT) < target)
            __builtin_amdgcn_s_sleep(2);
        __threadfence();                                   // acquire other blocks' writes
    }
    __syncthreads();
}

// ---------------- fused prep: X0 convert + Wfrag pack + cnt/bar zero ----------------
__global__ void prep_kernel(const float* __restrict__ x, uint_t* __restrict__ X0,
                            const float* __restrict__ W, ushort_t* __restrict__ Wfrag,
                            int* __restrict__ cnt) {
    int blk = blockIdx.x;
    if (blk < 20000) {
        int idx = blk * 256 + threadIdx.x;      // over N_V*B_*32
        int f2 = idx & 31;
        int b  = (idx >> 5) & 7;
        int n  = idx >> 8;
        float2 v = *(const float2*)&x[((size_t)b * N_V + n) * F_ + f2 * 2];
        X0[n * 256 + b * 32 + f2] = pack2(v.x, v.y);
    } else if (blk < 20096) {
        int idx = (blk - 20000) * 256 + threadIdx.x;
        if (idx < 12 * 4 * 64 * 8) {
            int j    = idx & 7;
            int lane = (idx >> 3) & 63;
            int ct   = (idx >> 9) & 3;
            int s    = idx >> 11;
            int o     = ct * 16 + (lane & 15);
            int kglob = s * 32 + ((lane >> 4) & 3) * 8 + j;
            Wfrag[idx] = f2bf(W[o * (K_ * F_) + kglob]);
        }
    } else {
        int i = (blk - 20096) * 256 + threadIdx.x;
        if (i < NPAIR + 1) cnt[i] = 0;          // cnt[NPAIR] is the barrier counter
    }
}

// ---------------- one SpMM phase: 1 row-pair per wave, batch-8 gathers ----------------
template <bool RECUR>
__device__ void spmm_phase(const int* __restrict__ cnt,
                           const int2* __restrict__ edges,
                           const ushort_t* __restrict__ Tprev,
                           const ushort_t* __restrict__ Tpp,
                           ushort_t* __restrict__ Tout) {
    const int wave = threadIdx.x >> 6, lane = threadIdx.x & 63;
    const int fo = lane * 8;                        // bf16 offset (16B per lane)

    for (int pair = blockIdx.x * 4 + wave; pair < NPAIR; pair += CHEB_WAVES) {
        const int n0 = pair * 2;
        const int st = pair * PCAP;
        const int en = st + min(cnt[pair], PCAP);

        float a0[8], a1[8];
#pragma unroll
        for (int i = 0; i < 8; ++i) { a0[i] = 0.f; a1[i] = 0.f; }

        for (int j = st; j < en; j += 8) {
            int2 E[8];
#pragma unroll
            for (int q = 0; q < 8; ++q) {
                E[q] = edges[min(j + q, en - 1)];
            }
            uint4 u[8];
#pragma unroll
            for (int q = 0; q < 8; ++q) {
                u[q] = *(const uint4*)(Tprev + (size_t)(E[q].x & 0x7FFF) * BF + fo);
            }
#pragma unroll
            for (int q = 0; q < 8; ++q) {
                const float v  = (j + q < en) ? __int_as_float(E[q].y) : 0.f;
                const float p0 = (E[q].x & 0x8000) ? 0.f : v;
                const float p1 = (E[q].x & 0x8000) ? v : 0.f;
                float e[8];
                unpack2(u[q].x, e[0], e[1]); unpack2(u[q].y, e[2], e[3]);
                unpack2(u[q].z, e[4], e[5]); unpack2(u[q].w, e[6], e[7]);
#pragma unroll
                for (int i = 0; i < 8; ++i) {
                    a0[i] = fmaf(p0, e[i], a0[i]);
                    a1[i] = fmaf(p1, e[i], a1[i]);
                }
            }
        }

        {
            float res[8];
#pragma unroll
            for (int i = 0; i < 8; ++i) res[i] = a0[i];
            if (RECUR) {
                uint4 up = *(const uint4*)(Tpp + (size_t)n0 * BF + fo);
                float ep[8];
                unpack2(up.x, ep[0], ep[1]); unpack2(up.y, ep[2], ep[3]);
                unpack2(up.z, ep[4], ep[5]); unpack2(up.w, ep[6], ep[7]);
#pragma unroll
                for (int i = 0; i < 8; ++i) res[i] = 2.f * res[i] - ep[i];
            }
            uint4 st4;
            st4.x = pack2(res[0], res[1]);
            st4.y = pack2(res[2], res[3]);
            st4.z = pack2(res[4], res[5]);
            st4.w = pack2(res[6], res[7]);
            *(uint4*)(Tout + (size_t)n0 * BF + fo) = st4;
        }
        {
            float res[8];
#pragma unroll
            for (int i = 0; i < 8; ++i) res[i] = a1[i];
            if (RECUR) {
                uint4 up = *(const uint4*)(Tpp + (size_t)(n0 + 1) * BF + fo);
                float ep[8];
                unpack2(up.x, ep[0], ep[1]); unpack2(up.y, ep[2], ep[3]);
                unpack2(up.z, ep[4], ep[5]); unpack2(up.w, ep[6], ep[7]);
#pragma unroll
                for (int i = 0; i < 8; ++i) res[i] = 2.f * res[i] - ep[i];
            }
            uint4 st4;
            st4.x = pack2(res[0], res[1]);
            st4.y = pack2(res[2], res[3]);
            st4.z = pack2(res[4], res[5]);
            st4.w = pack2(res[6], res[7]);
            *(uint4*)(Tout + (size_t)(n0 + 1) * BF + fo) = st4;
        }
    }
}

// ---------------- fused: scatter + 5 chained SpMMs, hand-rolled grid barriers ----------------
__global__ __launch_bounds__(256, 8) void cheb_fused(const int* __restrict__ rows,
                                                     const int* __restrict__ cols,
                                                     const float* __restrict__ vals,
                                                     int* __restrict__ cnt,
                                                     int* __restrict__ bar,
                                                     int2* __restrict__ edges,
                                                     const ushort_t* __restrict__ X0,
                                                     ushort_t* __restrict__ T1,
                                                     ushort_t* __restrict__ T2,
                                                     ushort_t* __restrict__ T3,
                                                     ushort_t* __restrict__ T4,
                                                     ushort_t* __restrict__ T5) {
    // phase 0: scatter (bump allocation into per-pair buckets), grid-stride
    for (int e = blockIdx.x * 256 + threadIdx.x; e < NNZ_; e += CHEB_BLOCKS * 256) {
        int c = cols[e];
        int r = rows[e];
        int pair = r >> 1;
        int pos = atomicAdd(&cnt[pair], 1);
        if (pos < PCAP) {                       // overflow guard (never fires statistically)
            int2 pe;
            pe.x = c | ((r & 1) << 15);
            pe.y = __float_as_int(vals[e]);
            edges[pair * PCAP + pos] = pe;
        }
    }
    gbar(bar, CHEB_BLOCKS);

    spmm_phase<false>(cnt, edges, X0, nullptr, T1);
    gbar(bar, 2 * CHEB_BLOCKS);
    spmm_phase<true >(cnt, edges, T1, X0, T2);
    gbar(bar, 3 * CHEB_BLOCKS);
    spmm_phase<true >(cnt, edges, T2, T1, T3);
    gbar(bar, 4 * CHEB_BLOCKS);
    spmm_phase<true >(cnt, edges, T3, T2, T4);
    gbar(bar, 5 * CHEB_BLOCKS);
    spmm_phase<true >(cnt, edges, T4, T3, T5);
}

// ---------------- FC via MFMA 16x16x32 bf16, 2 tiles/wave ----------------
__global__ __launch_bounds__(256) void fc_mfma(const ushort_t* __restrict__ X0,
                                               const ushort_t* __restrict__ T1,
                                               const ushort_t* __restrict__ T2,
                                               const ushort_t* __restrict__ T3,
                                               const ushort_t* __restrict__ T4,
                                               const ushort_t* __restrict__ T5,
                                               const ushort_t* __restrict__ Wfrag,
                                               const float* __restrict__ bias,
                                               float* __restrict__ out) {
    const int wave = threadIdx.x >> 6, lane = threadIdx.x & 63;
    const int quad = lane >> 4, col = lane & 15;
    const int tb = blockIdx.x * 128 + wave * 32;      // 2 tiles: tb, tb+16
    const int r0 = tb + col, r1 = tb + 16 + col;
    const ushort_t* Tbuf[6] = {X0, T1, T2, T3, T4, T5};

    frag_cd acc0[4], acc1[4];
#pragma unroll
    for (int ct = 0; ct < 4; ++ct) {
        acc0[ct] = (frag_cd){0.f, 0.f, 0.f, 0.f};
        acc1[ct] = (frag_cd){0.f, 0.f, 0.f, 0.f};
    }

#pragma unroll
    for (int s = 0; s < 12; ++s) {
        const int f0 = (s & 1) * 32 + quad * 8;
        frag_ab fa0 = *(const frag_ab*)(Tbuf[s >> 1] + (size_t)r0 * F_ + f0);
        frag_ab fa1 = *(const frag_ab*)(Tbuf[s >> 1] + (size_t)r1 * F_ + f0);
#pragma unroll
        for (int ct = 0; ct < 4; ++ct) {
            frag_ab bfr = *(const frag_ab*)(Wfrag + (((s * 4 + ct) * 64 + lane) << 3));
            acc0[ct] = __builtin_amdgcn_mfma_f32_16x16x32_bf16(fa0, bfr, acc0[ct], 0, 0, 0);
            acc1[ct] = __builtin_amdgcn_mfma_f32_16x16x32_bf16(fa1, bfr, acc1[ct], 0, 0, 0);
        }
    }

    // C/D: col = lane&15, row = quad*4 + reg
#pragma unroll
    for (int ct = 0; ct < 4; ++ct) {
        const int o = ct * 16 + col;
        const float bv = bias[o];
#pragma unroll
        for (int reg = 0; reg < 4; ++reg) {
            int ra = tb + quad * 4 + reg;
            int rb = ra + 16;
            out[(size_t)(ra & 7) * N_V * OUT_ + (size_t)(ra >> 3) * OUT_ + o] = acc0[ct][reg] + bv;
            out[(size_t)(rb & 7) * N_V * OUT_ + (size_t)(rb >> 3) * OUT_ + o] = acc1[ct][reg] + bv;
        }
    }
}

// ---------------- launcher ----------------

extern "C" void kernel_launch(void* const* d_in, const int* in_sizes, int n_in,
                              void* d_out, int out_size, void* d_ws, size_t ws_size,
                              hipStream_t stream) {
    const float* x    = (const float*)d_in[0];
    const int*   rows = (const int*)  d_in[1];
    const int*   cols = (const int*)  d_in[2];
    const float* vals = (const float*)d_in[3];
    const float* W    = (const float*)d_in[4];
    const float* bias = (const float*)d_in[5];
    float* out = (float*)d_out;

    const size_t TSZ = (size_t)N_V * BF;           // bf16 elements per T buffer
    ushort_t* T1 = (ushort_t*)d_ws;
    ushort_t* T2 = T1 + TSZ;
    ushort_t* T3 = T2 + TSZ;
    ushort_t* T4 = T3 + TSZ;
    ushort_t* T5 = T4 + TSZ;
    ushort_t* X0 = T5 + TSZ;
    ushort_t* Wfrag = X0 + TSZ;                    // 24576 ushorts
    int*  cnt   = (int*)(Wfrag + 24576);           // NPAIR counters + barrier + pad
    int*  bar   = cnt + NPAIR;                     // barrier counter (zeroed by prep)
    int2* edges = (int2*)(cnt + NPAIR + 64);       // NPAIR * PCAP int2

    prep_kernel<<<20136, 256, 0, stream>>>(x, (uint_t*)X0, W, Wfrag, cnt);

    cheb_fused<<<CHEB_BLOCKS, 256, 0, stream>>>(rows, cols, vals, cnt, bar, edges,
                                                X0, T1, T2, T3, T4, T5);

    fc_mfma<<<(N_V * B_) / 128, 256, 0, stream>>>(X0, T1, T2, T3, T4, T5, Wfrag, bias, out);
}

// Round 12
// 2633.750 us; speedup vs baseline: 1.1304x; 1.1304x over previous
//
#include <hip/hip_runtime.h>

#define N_V  20000
#define B_   8
#define F_   64
#define K_   6
#define OUT_ 64
#define NNZ_ 320000
#define BF   512    // B_*F_
#define NPAIR (N_V / 2)            // 10000 row pairs
#define PCAP 128                   // edge capacity per pair (P(overflow) ~ 1e-40)
#define CHEB_BLOCKS 1024           // 4 blocks/CU needed; capacity 8/CU at <=64 VGPR (2x slack)
#define CHEB_WAVES  (CHEB_BLOCKS * 4)

typedef unsigned short ushort_t;
typedef unsigned int   uint_t;

using frag_ab = __attribute__((ext_vector_type(8))) short;  // 8 bf16 (4 VGPRs)
using frag_cd = __attribute__((ext_vector_type(4))) float;  // 4 f32 acc

// ---- bf16 helpers ----
__device__ __forceinline__ ushort_t f2bf(float f) {          // round-to-nearest-even
    uint_t u = __float_as_uint(f);
    u += 0x7FFFu + ((u >> 16) & 1u);
    return (ushort_t)(u >> 16);
}
__device__ __forceinline__ uint_t pack2(float lo, float hi) {
    return (uint_t)f2bf(lo) | ((uint_t)f2bf(hi) << 16);
}
__device__ __forceinline__ void unpack2(uint_t u, float& lo, float& hi) {
    lo = __uint_as_float(u << 16);
    hi = __uint_as_float(u & 0xFFFF0000u);
}

// ---- hand-rolled grid barrier (monotonic counter, device scope) ----
// All CHEB_BLOCKS blocks are co-resident by construction (see launch config),
// so spinning is deadlock-free. Phase p waits for bar >= p * CHEB_BLOCKS.
// R11 lesson: s_sleep(2) polling saturated the fabric (1.2 TB/s of cacheline
// traffic from 1024 spinners). s_sleep(64) ~ 1.7us/poll -> ~38 GB/s, invisible.
__device__ __forceinline__ void gbar(int* __restrict__ bar, int target) {
    __syncthreads();
    if (threadIdx.x == 0) {
        __threadfence();                                   // release prior writes (agent scope)
        __hip_atomic_fetch_add(bar, 1, __ATOMIC_ACQ_REL, __HIP_MEMORY_SCOPE_AGENT);
        while (__hip_atomic_load(bar, __ATOMIC_ACQUIRE, __HIP_MEMORY_SCOPE_AGENT) < target)
            __builtin_amdgcn_s_sleep(64);
        __threadfence();                                   // acquire other blocks' writes
    }
    __syncthreads();
}

// ---------------- fused prep: X0 convert + Wfrag pack + cnt/bar zero ----------------
__global__ void prep_kernel(const float* __restrict__ x, uint_t* __restrict__ X0,
                            const float* __restrict__ W, ushort_t* __restrict__ Wfrag,
                            int* __restrict__ cnt) {
    int blk = blockIdx.x;
    if (blk < 20000) {
        int idx = blk * 256 + threadIdx.x;      // over N_V*B_*32
        int f2 = idx & 31;
        int b  = (idx >> 5) & 7;
        int n  = idx >> 8;
        float2 v = *(const float2*)&x[((size_t)b * N_V + n) * F_ + f2 * 2];
        X0[n * 256 + b * 32 + f2] = pack2(v.x, v.y);
    } else if (blk < 20096) {
        int idx = (blk - 20000) * 256 + threadIdx.x;
        if (idx < 12 * 4 * 64 * 8) {
            int j    = idx & 7;
            int lane = (idx >> 3) & 63;
            int ct   = (idx >> 9) & 3;
            int s    = idx >> 11;
            int o     = ct * 16 + (lane & 15);
            int kglob = s * 32 + ((lane >> 4) & 3) * 8 + j;
            Wfrag[idx] = f2bf(W[o * (K_ * F_) + kglob]);
        }
    } else {
        int i = (blk - 20096) * 256 + threadIdx.x;
        if (i < NPAIR + 1) cnt[i] = 0;          // cnt[NPAIR] is the barrier counter
    }
}

// ---------------- one SpMM phase: 1 row-pair per wave, batch-8 gathers ----------------
template <bool RECUR>
__device__ void spmm_phase(const int* __restrict__ cnt,
                           const int2* __restrict__ edges,
                           const ushort_t* __restrict__ Tprev,
                           const ushort_t* __restrict__ Tpp,
                           ushort_t* __restrict__ Tout) {
    const int wave = threadIdx.x >> 6, lane = threadIdx.x & 63;
    const int fo = lane * 8;                        // bf16 offset (16B per lane)

    for (int pair = blockIdx.x * 4 + wave; pair < NPAIR; pair += CHEB_WAVES) {
        const int n0 = pair * 2;
        const int st = pair * PCAP;
        const int en = st + min(cnt[pair], PCAP);

        float a0[8], a1[8];
#pragma unroll
        for (int i = 0; i < 8; ++i) { a0[i] = 0.f; a1[i] = 0.f; }

        for (int j = st; j < en; j += 8) {
            int2 E[8];
#pragma unroll
            for (int q = 0; q < 8; ++q) {
                E[q] = edges[min(j + q, en - 1)];
            }
            uint4 u[8];
#pragma unroll
            for (int q = 0; q < 8; ++q) {
                u[q] = *(const uint4*)(Tprev + (size_t)(E[q].x & 0x7FFF) * BF + fo);
            }
#pragma unroll
            for (int q = 0; q < 8; ++q) {
                const float v  = (j + q < en) ? __int_as_float(E[q].y) : 0.f;
                const float p0 = (E[q].x & 0x8000) ? 0.f : v;
                const float p1 = (E[q].x & 0x8000) ? v : 0.f;
                float e[8];
                unpack2(u[q].x, e[0], e[1]); unpack2(u[q].y, e[2], e[3]);
                unpack2(u[q].z, e[4], e[5]); unpack2(u[q].w, e[6], e[7]);
#pragma unroll
                for (int i = 0; i < 8; ++i) {
                    a0[i] = fmaf(p0, e[i], a0[i]);
                    a1[i] = fmaf(p1, e[i], a1[i]);
                }
            }
        }

        {
            float res[8];
#pragma unroll
            for (int i = 0; i < 8; ++i) res[i] = a0[i];
            if (RECUR) {
                uint4 up = *(const uint4*)(Tpp + (size_t)n0 * BF + fo);
                float ep[8];
                unpack2(up.x, ep[0], ep[1]); unpack2(up.y, ep[2], ep[3]);
                unpack2(up.z, ep[4], ep[5]); unpack2(up.w, ep[6], ep[7]);
#pragma unroll
                for (int i = 0; i < 8; ++i) res[i] = 2.f * res[i] - ep[i];
            }
            uint4 st4;
            st4.x = pack2(res[0], res[1]);
            st4.y = pack2(res[2], res[3]);
            st4.z = pack2(res[4], res[5]);
            st4.w = pack2(res[6], res[7]);
            *(uint4*)(Tout + (size_t)n0 * BF + fo) = st4;
        }
        {
            float res[8];
#pragma unroll
            for (int i = 0; i < 8; ++i) res[i] = a1[i];
            if (RECUR) {
                uint4 up = *(const uint4*)(Tpp + (size_t)(n0 + 1) * BF + fo);
                float ep[8];
                unpack2(up.x, ep[0], ep[1]); unpack2(up.y, ep[2], ep[3]);
                unpack2(up.z, ep[4], ep[5]); unpack2(up.w, ep[6], ep[7]);
#pragma unroll
                for (int i = 0; i < 8; ++i) res[i] = 2.f * res[i] - ep[i];
            }
            uint4 st4;
            st4.x = pack2(res[0], res[1]);
            st4.y = pack2(res[2], res[3]);
            st4.z = pack2(res[4], res[5]);
            st4.w = pack2(res[6], res[7]);
            *(uint4*)(Tout + (size_t)(n0 + 1) * BF + fo) = st4;
        }
    }
}

// ---------------- fused: scatter + 5 chained SpMMs, hand-rolled grid barriers ----------------
__global__ __launch_bounds__(256, 8) void cheb_fused(const int* __restrict__ rows,
                                                     const int* __restrict__ cols,
                                                     const float* __restrict__ vals,
                                                     int* __restrict__ cnt,
                                                     int* __restrict__ bar,
                                                     int2* __restrict__ edges,
                                                     const ushort_t* __restrict__ X0,
                                                     ushort_t* __restrict__ T1,
                                                     ushort_t* __restrict__ T2,
                                                     ushort_t* __restrict__ T3,
                                                     ushort_t* __restrict__ T4,
                                                     ushort_t* __restrict__ T5) {
    // phase 0: scatter (bump allocation into per-pair buckets), grid-stride
    for (int e = blockIdx.x * 256 + threadIdx.x; e < NNZ_; e += CHEB_BLOCKS * 256) {
        int c = cols[e];
        int r = rows[e];
        int pair = r >> 1;
        int pos = atomicAdd(&cnt[pair], 1);
        if (pos < PCAP) {                       // overflow guard (never fires statistically)
            int2 pe;
            pe.x = c | ((r & 1) << 15);
            pe.y = __float_as_int(vals[e]);
            edges[pair * PCAP + pos] = pe;
        }
    }
    gbar(bar, CHEB_BLOCKS);

    spmm_phase<false>(cnt, edges, X0, nullptr, T1);
    gbar(bar, 2 * CHEB_BLOCKS);
    spmm_phase<true >(cnt, edges, T1, X0, T2);
    gbar(bar, 3 * CHEB_BLOCKS);
    spmm_phase<true >(cnt, edges, T2, T1, T3);
    gbar(bar, 4 * CHEB_BLOCKS);
    spmm_phase<true >(cnt, edges, T3, T2, T4);
    gbar(bar, 5 * CHEB_BLOCKS);
    spmm_phase<true >(cnt, edges, T4, T3, T5);
}

// ---------------- FC via MFMA 16x16x32 bf16, 2 tiles/wave ----------------
__global__ __launch_bounds__(256) void fc_mfma(const ushort_t* __restrict__ X0,
                                               const ushort_t* __restrict__ T1,
                                               const ushort_t* __restrict__ T2,
                                               const ushort_t* __restrict__ T3,
                                               const ushort_t* __restrict__ T4,
                                               const ushort_t* __restrict__ T5,
                                               const ushort_t* __restrict__ Wfrag,
                                               const float* __restrict__ bias,
                                               float* __restrict__ out) {
    const int wave = threadIdx.x >> 6, lane = threadIdx.x & 63;
    const int quad = lane >> 4, col = lane & 15;
    const int tb = blockIdx.x * 128 + wave * 32;      // 2 tiles: tb, tb+16
    const int r0 = tb + col, r1 = tb + 16 + col;
    const ushort_t* Tbuf[6] = {X0, T1, T2, T3, T4, T5};

    frag_cd acc0[4], acc1[4];
#pragma unroll
    for (int ct = 0; ct < 4; ++ct) {
        acc0[ct] = (frag_cd){0.f, 0.f, 0.f, 0.f};
        acc1[ct] = (frag_cd){0.f, 0.f, 0.f, 0.f};
    }

#pragma unroll
    for (int s = 0; s < 12; ++s) {
        const int f0 = (s & 1) * 32 + quad * 8;
        frag_ab fa0 = *(const frag_ab*)(Tbuf[s >> 1] + (size_t)r0 * F_ + f0);
        frag_ab fa1 = *(const frag_ab*)(Tbuf[s >> 1] + (size_t)r1 * F_ + f0);
#pragma unroll
        for (int ct = 0; ct < 4; ++ct) {
            frag_ab bfr = *(const frag_ab*)(Wfrag + (((s * 4 + ct) * 64 + lane) << 3));
            acc0[ct] = __builtin_amdgcn_mfma_f32_16x16x32_bf16(fa0, bfr, acc0[ct], 0, 0, 0);
            acc1[ct] = __builtin_amdgcn_mfma_f32_16x16x32_bf16(fa1, bfr, acc1[ct], 0, 0, 0);
        }
    }

    // C/D: col = lane&15, row = quad*4 + reg
#pragma unroll
    for (int ct = 0; ct < 4; ++ct) {
        const int o = ct * 16 + col;
        const float bv = bias[o];
#pragma unroll
        for (int reg = 0; reg < 4; ++reg) {
            int ra = tb + quad * 4 + reg;
            int rb = ra + 16;
            out[(size_t)(ra & 7) * N_V * OUT_ + (size_t)(ra >> 3) * OUT_ + o] = acc0[ct][reg] + bv;
            out[(size_t)(rb & 7) * N_V * OUT_ + (size_t)(rb >> 3) * OUT_ + o] = acc1[ct][reg] + bv;
        }
    }
}

// ---------------- launcher ----------------

extern "C" void kernel_launch(void* const* d_in, const int* in_sizes, int n_in,
                              void* d_out, int out_size, void* d_ws, size_t ws_size,
                              hipStream_t stream) {
    const float* x    = (const float*)d_in[0];
    const int*   rows = (const int*)  d_in[1];
    const int*   cols = (const int*)  d_in[2];
    const float* vals = (const float*)d_in[3];
    const float* W    = (const float*)d_in[4];
    const float* bias = (const float*)d_in[5];
    float* out = (float*)d_out;

    const size_t TSZ = (size_t)N_V * BF;           // bf16 elements per T buffer
    ushort_t* T1 = (ushort_t*)d_ws;
    ushort_t* T2 = T1 + TSZ;
    ushort_t* T3 = T2 + TSZ;
    ushort_t* T4 = T3 + TSZ;
    ushort_t* T5 = T4 + TSZ;
    ushort_t* X0 = T5 + TSZ;
    ushort_t* Wfrag = X0 + TSZ;                    // 24576 ushorts
    int*  cnt   = (int*)(Wfrag + 24576);           // NPAIR counters + barrier + pad
    int*  bar   = cnt + NPAIR;                     // barrier counter (zeroed by prep)
    int2* edges = (int2*)(cnt + NPAIR + 64);       // NPAIR * PCAP int2

    prep_kernel<<<20136, 256, 0, stream>>>(x, (uint_t*)X0, W, Wfrag, cnt);

    cheb_fused<<<CHEB_BLOCKS, 256, 0, stream>>>(rows, cols, vals, cnt, bar, edges,
                                                X0, T1, T2, T3, T4, T5);

    fc_mfma<<<(N_V * B_) / 128, 256, 0, stream>>>(X0, T1, T2, T3, T4, T5, Wfrag, bias, out);
}

// Round 13
// 396.348 us; speedup vs baseline: 7.5118x; 6.6450x over previous
//
#include <hip/hip_runtime.h>

#define N_V  20000
#define B_   8
#define F_   64
#define K_   6
#define OUT_ 64
#define NNZ_ 320000
#define BF   512    // B_*F_
#define NPAIR (N_V / 2)            // 10000 row pairs
#define PCAP 128                   // edge capacity per pair (P(overflow) ~ 1e-40)
#define CHEB_WAVES 8192            // 2048 blocks x 4 waves

typedef unsigned short ushort_t;
typedef unsigned int   uint_t;

using frag_ab = __attribute__((ext_vector_type(8))) short;  // 8 bf16 (4 VGPRs)
using frag_cd = __attribute__((ext_vector_type(4))) float;  // 4 f32 acc

// ---- bf16 helpers ----
__device__ __forceinline__ ushort_t f2bf(float f) {          // round-to-nearest-even
    uint_t u = __float_as_uint(f);
    u += 0x7FFFu + ((u >> 16) & 1u);
    return (ushort_t)(u >> 16);
}
__device__ __forceinline__ uint_t pack2(float lo, float hi) {
    return (uint_t)f2bf(lo) | ((uint_t)f2bf(hi) << 16);
}
__device__ __forceinline__ void unpack2(uint_t u, float& lo, float& hi) {
    lo = __uint_as_float(u << 16);
    hi = __uint_as_float(u & 0xFFFF0000u);
}

// ---------------- fused prep: X0 convert + Wfrag pack + cnt zero ----------------
__global__ void prep_kernel(const float* __restrict__ x, uint_t* __restrict__ X0,
                            const float* __restrict__ W, ushort_t* __restrict__ Wfrag,
                            int* __restrict__ cnt) {
    int blk = blockIdx.x;
    if (blk < 20000) {
        int idx = blk * 256 + threadIdx.x;      // over N_V*B_*32
        int f2 = idx & 31;
        int b  = (idx >> 5) & 7;
        int n  = idx >> 8;
        float2 v = *(const float2*)&x[((size_t)b * N_V + n) * F_ + f2 * 2];
        X0[n * 256 + b * 32 + f2] = pack2(v.x, v.y);
    } else if (blk < 20096) {
        int idx = (blk - 20000) * 256 + threadIdx.x;
        if (idx < 12 * 4 * 64 * 8) {
            int j    = idx & 7;
            int lane = (idx >> 3) & 63;
            int ct   = (idx >> 9) & 3;
            int s    = idx >> 11;
            int o     = ct * 16 + (lane & 15);
            int kglob = s * 32 + ((lane >> 4) & 3) * 8 + j;
            Wfrag[idx] = f2bf(W[o * (K_ * F_) + kglob]);
        }
    } else {
        int i = (blk - 20096) * 256 + threadIdx.x;
        if (i < NPAIR) cnt[i] = 0;
    }
}

// ---------------- scatter with fixed-capacity bump allocation ----------------
// edges packed: {col | (row&1)<<15, val_bits}   (col < 20000 < 2^15)
__global__ void scatter_kernel(const int* __restrict__ rows, const int* __restrict__ cols,
                               const float* __restrict__ vals, int* __restrict__ cnt,
                               int2* __restrict__ edges) {
    int e = blockIdx.x * 256 + threadIdx.x;
    if (e < NNZ_) {
        int c = cols[e];
        int r = rows[e];
        int pair = r >> 1;
        int pos = atomicAdd(&cnt[pair], 1);
        if (pos < PCAP) {                       // overflow guard (never fires statistically)
            int2 pe;
            pe.x = c | ((r & 1) << 15);
            pe.y = __float_as_int(vals[e]);
            edges[pair * PCAP + pos] = pe;
        }
    }
}

// -------- SpMM: 1 row-pair per wave; full blocks of 16 edges in flight, batch-8 tail --------
template <bool RECUR>
__global__ __launch_bounds__(256, 4) void cheb_pair(const int* __restrict__ cnt,
                                                    const int2* __restrict__ edges,
                                                    const ushort_t* __restrict__ Tprev,
                                                    const ushort_t* __restrict__ Tpp,
                                                    ushort_t* __restrict__ Tout) {
    const int wave = threadIdx.x >> 6, lane = threadIdx.x & 63;
    const int fo = lane * 8;                        // bf16 offset (16B per lane)

    for (int pair = blockIdx.x * 4 + wave; pair < NPAIR; pair += CHEB_WAVES) {
        const int n0 = pair * 2;
        const int st = pair * PCAP;
        const int en = st + min(cnt[pair], PCAP);

        float a0[8], a1[8];
#pragma unroll
        for (int i = 0; i < 8; ++i) { a0[i] = 0.f; a1[i] = 0.f; }

        int j = st;
        // ---- full blocks: 16 edges, vectorized edge loads, 16 gathers in flight ----
        for (; j + 16 <= en; j += 16) {
            const int4* ep = (const int4*)(edges + j);   // 128B-aligned (st % 128 == 0)
            uint4 u[16];
            float p0v[16], p1v[16];
#pragma unroll
            for (int q = 0; q < 8; ++q) {
                int4 ev = ep[q];                         // edges 2q, 2q+1
                u[2 * q]     = *(const uint4*)(Tprev + (size_t)(ev.x & 0x7FFF) * BF + fo);
                u[2 * q + 1] = *(const uint4*)(Tprev + (size_t)(ev.z & 0x7FFF) * BF + fo);
                const float va = __int_as_float(ev.y);
                const float vb = __int_as_float(ev.w);
                p0v[2 * q]     = (ev.x & 0x8000) ? 0.f : va;
                p1v[2 * q]     = (ev.x & 0x8000) ? va : 0.f;
                p0v[2 * q + 1] = (ev.z & 0x8000) ? 0.f : vb;
                p1v[2 * q + 1] = (ev.z & 0x8000) ? vb : 0.f;
            }
#pragma unroll
            for (int q = 0; q < 16; ++q) {
                float e[8];
                unpack2(u[q].x, e[0], e[1]); unpack2(u[q].y, e[2], e[3]);
                unpack2(u[q].z, e[4], e[5]); unpack2(u[q].w, e[6], e[7]);
#pragma unroll
                for (int i = 0; i < 8; ++i) {
                    a0[i] = fmaf(p0v[q], e[i], a0[i]);
                    a1[i] = fmaf(p1v[q], e[i], a1[i]);
                }
            }
        }
        // ---- tail: clamped batch-8 (R9's proven path), <=2 iterations ----
        for (; j < en; j += 8) {
            int2 E[8];
#pragma unroll
            for (int q = 0; q < 8; ++q) {
                E[q] = edges[min(j + q, en - 1)];
            }
            uint4 u[8];
#pragma unroll
            for (int q = 0; q < 8; ++q) {
                u[q] = *(const uint4*)(Tprev + (size_t)(E[q].x & 0x7FFF) * BF + fo);
            }
#pragma unroll
            for (int q = 0; q < 8; ++q) {
                const float v  = (j + q < en) ? __int_as_float(E[q].y) : 0.f;
                const float p0 = (E[q].x & 0x8000) ? 0.f : v;
                const float p1 = (E[q].x & 0x8000) ? v : 0.f;
                float e[8];
                unpack2(u[q].x, e[0], e[1]); unpack2(u[q].y, e[2], e[3]);
                unpack2(u[q].z, e[4], e[5]); unpack2(u[q].w, e[6], e[7]);
#pragma unroll
                for (int i = 0; i < 8; ++i) {
                    a0[i] = fmaf(p0, e[i], a0[i]);
                    a1[i] = fmaf(p1, e[i], a1[i]);
                }
            }
        }

        // epilogue: row n0 from a0, row n0+1 from a1
        {
            float res[8];
#pragma unroll
            for (int i = 0; i < 8; ++i) res[i] = a0[i];
            if (RECUR) {
                uint4 up = *(const uint4*)(Tpp + (size_t)n0 * BF + fo);
                float ep[8];
                unpack2(up.x, ep[0], ep[1]); unpack2(up.y, ep[2], ep[3]);
                unpack2(up.z, ep[4], ep[5]); unpack2(up.w, ep[6], ep[7]);
#pragma unroll
                for (int i = 0; i < 8; ++i) res[i] = 2.f * res[i] - ep[i];
            }
            uint4 st4;
            st4.x = pack2(res[0], res[1]);
            st4.y = pack2(res[2], res[3]);
            st4.z = pack2(res[4], res[5]);
            st4.w = pack2(res[6], res[7]);
            *(uint4*)(Tout + (size_t)n0 * BF + fo) = st4;
        }
        {
            float res[8];
#pragma unroll
            for (int i = 0; i < 8; ++i) res[i] = a1[i];
            if (RECUR) {
                uint4 up = *(const uint4*)(Tpp + (size_t)(n0 + 1) * BF + fo);
                float ep[8];
                unpack2(up.x, ep[0], ep[1]); unpack2(up.y, ep[2], ep[3]);
                unpack2(up.z, ep[4], ep[5]); unpack2(up.w, ep[6], ep[7]);
#pragma unroll
                for (int i = 0; i < 8; ++i) res[i] = 2.f * res[i] - ep[i];
            }
            uint4 st4;
            st4.x = pack2(res[0], res[1]);
            st4.y = pack2(res[2], res[3]);
            st4.z = pack2(res[4], res[5]);
            st4.w = pack2(res[6], res[7]);
            *(uint4*)(Tout + (size_t)(n0 + 1) * BF + fo) = st4;
        }
    }
}

// ---------------- FC via MFMA 16x16x32 bf16, 2 tiles/wave ----------------
__global__ __launch_bounds__(256) void fc_mfma(const ushort_t* __restrict__ X0,
                                               const ushort_t* __restrict__ T1,
                                               const ushort_t* __restrict__ T2,
                                               const ushort_t* __restrict__ T3,
                                               const ushort_t* __restrict__ T4,
                                               const ushort_t* __restrict__ T5,
                                               const ushort_t* __restrict__ Wfrag,
                                               const float* __restrict__ bias,
                                               float* __restrict__ out) {
    const int wave = threadIdx.x >> 6, lane = threadIdx.x & 63;
    const int quad = lane >> 4, col = lane & 15;
    const int tb = blockIdx.x * 128 + wave * 32;      // 2 tiles: tb, tb+16
    const int r0 = tb + col, r1 = tb + 16 + col;
    const ushort_t* Tbuf[6] = {X0, T1, T2, T3, T4, T5};

    frag_cd acc0[4], acc1[4];
#pragma unroll
    for (int ct = 0; ct < 4; ++ct) {
        acc0[ct] = (frag_cd){0.f, 0.f, 0.f, 0.f};
        acc1[ct] = (frag_cd){0.f, 0.f, 0.f, 0.f};
    }

#pragma unroll
    for (int s = 0; s < 12; ++s) {
        const int f0 = (s & 1) * 32 + quad * 8;
        frag_ab fa0 = *(const frag_ab*)(Tbuf[s >> 1] + (size_t)r0 * F_ + f0);
        frag_ab fa1 = *(const frag_ab*)(Tbuf[s >> 1] + (size_t)r1 * F_ + f0);
#pragma unroll
        for (int ct = 0; ct < 4; ++ct) {
            frag_ab bfr = *(const frag_ab*)(Wfrag + (((s * 4 + ct) * 64 + lane) << 3));
            acc0[ct] = __builtin_amdgcn_mfma_f32_16x16x32_bf16(fa0, bfr, acc0[ct], 0, 0, 0);
            acc1[ct] = __builtin_amdgcn_mfma_f32_16x16x32_bf16(fa1, bfr, acc1[ct], 0, 0, 0);
        }
    }

    // C/D: col = lane&15, row = quad*4 + reg
#pragma unroll
    for (int ct = 0; ct < 4; ++ct) {
        const int o = ct * 16 + col;
        const float bv = bias[o];
#pragma unroll
        for (int reg = 0; reg < 4; ++reg) {
            int ra = tb + quad * 4 + reg;
            int rb = ra + 16;
            out[(size_t)(ra & 7) * N_V * OUT_ + (size_t)(ra >> 3) * OUT_ + o] = acc0[ct][reg] + bv;
            out[(size_t)(rb & 7) * N_V * OUT_ + (size_t)(rb >> 3) * OUT_ + o] = acc1[ct][reg] + bv;
        }
    }
}

// ---------------- launcher ----------------

extern "C" void kernel_launch(void* const* d_in, const int* in_sizes, int n_in,
                              void* d_out, int out_size, void* d_ws, size_t ws_size,
                              hipStream_t stream) {
    const float* x    = (const float*)d_in[0];
    const int*   rows = (const int*)  d_in[1];
    const int*   cols = (const int*)  d_in[2];
    const float* vals = (const float*)d_in[3];
    const float* W    = (const float*)d_in[4];
    const float* bias = (const float*)d_in[5];
    float* out = (float*)d_out;

    const size_t TSZ = (size_t)N_V * BF;           // bf16 elements per T buffer
    ushort_t* T1 = (ushort_t*)d_ws;
    ushort_t* T2 = T1 + TSZ;
    ushort_t* T3 = T2 + TSZ;
    ushort_t* T4 = T3 + TSZ;
    ushort_t* T5 = T4 + TSZ;
    ushort_t* X0 = T5 + TSZ;
    ushort_t* Wfrag = X0 + TSZ;                    // 24576 ushorts
    int*  cnt   = (int*)(Wfrag + 24576);           // NPAIR counters
    int2* edges = (int2*)(cnt + NPAIR + 64);       // NPAIR * PCAP int2

    prep_kernel<<<20136, 256, 0, stream>>>(x, (uint_t*)X0, W, Wfrag, cnt);
    scatter_kernel<<<(NNZ_ + 255) / 256, 256, 0, stream>>>(rows, cols, vals, cnt, edges);

    cheb_pair<false><<<CHEB_WAVES / 4, 256, 0, stream>>>(cnt, edges, X0, nullptr, T1);
    cheb_pair<true ><<<CHEB_WAVES / 4, 256, 0, stream>>>(cnt, edges, T1, X0, T2);
    cheb_pair<true ><<<CHEB_WAVES / 4, 256, 0, stream>>>(cnt, edges, T2, T1, T3);
    cheb_pair<true ><<<CHEB_WAVES / 4, 256, 0, stream>>>(cnt, edges, T3, T2, T4);
    cheb_pair<true ><<<CHEB_WAVES / 4, 256, 0, stream>>>(cnt, edges, T4, T3, T5);

    fc_mfma<<<(N_V * B_) / 128, 256, 0, stream>>>(X0, T1, T2, T3, T4, T5, Wfrag, bias, out);
}

// Round 14
// 382.911 us; speedup vs baseline: 7.7754x; 1.0351x over previous
//
#include <hip/hip_runtime.h>

#define N_V  20000
#define B_   8
#define F_   64
#define K_   6
#define OUT_ 64
#define NNZ_ 320000
#define BF   512    // B_*F_
#define NPAIR (N_V / 2)            // 10000 row pairs
#define PCAP 128                   // edge capacity per pair (P(overflow) ~ 1e-40)
#define CHEB_WAVES 8192            // 2048 blocks x 4 waves

typedef unsigned short ushort_t;
typedef unsigned int   uint_t;

using frag_ab = __attribute__((ext_vector_type(8))) short;  // 8 bf16 (4 VGPRs)
using frag_cd = __attribute__((ext_vector_type(4))) float;  // 4 f32 acc

// ---- bf16 helpers ----
__device__ __forceinline__ ushort_t f2bf(float f) {          // round-to-nearest-even
    uint_t u = __float_as_uint(f);
    u += 0x7FFFu + ((u >> 16) & 1u);
    return (ushort_t)(u >> 16);
}
__device__ __forceinline__ uint_t pack2(float lo, float hi) {
    return (uint_t)f2bf(lo) | ((uint_t)f2bf(hi) << 16);
}
__device__ __forceinline__ void unpack2(uint_t u, float& lo, float& hi) {
    lo = __uint_as_float(u << 16);
    hi = __uint_as_float(u & 0xFFFF0000u);
}

// ---------------- fused prep: X0 convert + Wfrag pack + cnt zero ----------------
__global__ void prep_kernel(const float* __restrict__ x, uint_t* __restrict__ X0,
                            const float* __restrict__ W, ushort_t* __restrict__ Wfrag,
                            int* __restrict__ cnt) {
    int blk = blockIdx.x;
    if (blk < 20000) {
        int idx = blk * 256 + threadIdx.x;      // over N_V*B_*32
        int f2 = idx & 31;
        int b  = (idx >> 5) & 7;
        int n  = idx >> 8;
        float2 v = *(const float2*)&x[((size_t)b * N_V + n) * F_ + f2 * 2];
        X0[n * 256 + b * 32 + f2] = pack2(v.x, v.y);
    } else if (blk < 20096) {
        int idx = (blk - 20000) * 256 + threadIdx.x;
        if (idx < 12 * 4 * 64 * 8) {
            int j    = idx & 7;
            int lane = (idx >> 3) & 63;
            int ct   = (idx >> 9) & 3;
            int s    = idx >> 11;
            int o     = ct * 16 + (lane & 15);
            int kglob = s * 32 + ((lane >> 4) & 3) * 8 + j;
            Wfrag[idx] = f2bf(W[o * (K_ * F_) + kglob]);
        }
    } else {
        int i = (blk - 20096) * 256 + threadIdx.x;
        if (i < NPAIR) cnt[i] = 0;
    }
}

// ---------------- scatter with fixed-capacity bump allocation (no hist/scan) ----------------
// edges packed: {col | (row&1)<<15, val_bits}   (col < 20000 < 2^15)
__global__ void scatter_kernel(const int* __restrict__ rows, const int* __restrict__ cols,
                               const float* __restrict__ vals, int* __restrict__ cnt,
                               int2* __restrict__ edges) {
    int e = blockIdx.x * 256 + threadIdx.x;
    if (e < NNZ_) {
        int c = cols[e];
        int r = rows[e];
        int pair = r >> 1;
        int pos = atomicAdd(&cnt[pair], 1);
        if (pos < PCAP) {                       // overflow guard (never fires statistically)
            int2 pe;
            pe.x = c | ((r & 1) << 15);
            pe.y = __float_as_int(vals[e]);
            edges[pair * PCAP + pos] = pe;
        }
    }
}

// -------- SpMM: 1 row-pair per wave, batch-8 gathers in flight, grid-stride pairs --------
template <bool RECUR>
__global__ __launch_bounds__(256) void cheb_pair(const int* __restrict__ cnt,
                                                 const int2* __restrict__ edges,
                                                 const ushort_t* __restrict__ Tprev,
                                                 const ushort_t* __restrict__ Tpp,
                                                 ushort_t* __restrict__ Tout) {
    const int wave = threadIdx.x >> 6, lane = threadIdx.x & 63;
    const int fo = lane * 8;                        // bf16 offset (16B per lane)

    for (int pair = blockIdx.x * 4 + wave; pair < NPAIR; pair += CHEB_WAVES) {
        const int n0 = pair * 2;
        const int st = pair * PCAP;
        const int en = st + min(cnt[pair], PCAP);

        float a0[8], a1[8];
#pragma unroll
        for (int i = 0; i < 8; ++i) { a0[i] = 0.f; a1[i] = 0.f; }

        for (int j = st; j < en; j += 8) {
            int2 E[8];
#pragma unroll
            for (int q = 0; q < 8; ++q) {
                E[q] = edges[min(j + q, en - 1)];
            }
            uint4 u[8];
#pragma unroll
            for (int q = 0; q < 8; ++q) {
                u[q] = *(const uint4*)(Tprev + (size_t)(E[q].x & 0x7FFF) * BF + fo);
            }
#pragma unroll
            for (int q = 0; q < 8; ++q) {
                const float v  = (j + q < en) ? __int_as_float(E[q].y) : 0.f;
                const float p0 = (E[q].x & 0x8000) ? 0.f : v;
                const float p1 = (E[q].x & 0x8000) ? v : 0.f;
                float e[8];
                unpack2(u[q].x, e[0], e[1]); unpack2(u[q].y, e[2], e[3]);
                unpack2(u[q].z, e[4], e[5]); unpack2(u[q].w, e[6], e[7]);
#pragma unroll
                for (int i = 0; i < 8; ++i) {
                    a0[i] = fmaf(p0, e[i], a0[i]);
                    a1[i] = fmaf(p1, e[i], a1[i]);
                }
            }
        }

        // epilogue: row n0 from a0, row n0+1 from a1
        {
            float res[8];
#pragma unroll
            for (int i = 0; i < 8; ++i) res[i] = a0[i];
            if (RECUR) {
                uint4 up = *(const uint4*)(Tpp + (size_t)n0 * BF + fo);
                float ep[8];
                unpack2(up.x, ep[0], ep[1]); unpack2(up.y, ep[2], ep[3]);
                unpack2(up.z, ep[4], ep[5]); unpack2(up.w, ep[6], ep[7]);
#pragma unroll
                for (int i = 0; i < 8; ++i) res[i] = 2.f * res[i] - ep[i];
            }
            uint4 st4;
            st4.x = pack2(res[0], res[1]);
            st4.y = pack2(res[2], res[3]);
            st4.z = pack2(res[4], res[5]);
            st4.w = pack2(res[6], res[7]);
            *(uint4*)(Tout + (size_t)n0 * BF + fo) = st4;
        }
        {
            float res[8];
#pragma unroll
            for (int i = 0; i < 8; ++i) res[i] = a1[i];
            if (RECUR) {
                uint4 up = *(const uint4*)(Tpp + (size_t)(n0 + 1) * BF + fo);
                float ep[8];
                unpack2(up.x, ep[0], ep[1]); unpack2(up.y, ep[2], ep[3]);
                unpack2(up.z, ep[4], ep[5]); unpack2(up.w, ep[6], ep[7]);
#pragma unroll
                for (int i = 0; i < 8; ++i) res[i] = 2.f * res[i] - ep[i];
            }
            uint4 st4;
            st4.x = pack2(res[0], res[1]);
            st4.y = pack2(res[2], res[3]);
            st4.z = pack2(res[4], res[5]);
            st4.w = pack2(res[6], res[7]);
            *(uint4*)(Tout + (size_t)(n0 + 1) * BF + fo) = st4;
        }
    }
}

// ---------------- FC via MFMA 16x16x32 bf16, 2 tiles/wave ----------------
__global__ __launch_bounds__(256) void fc_mfma(const ushort_t* __restrict__ X0,
                                               const ushort_t* __restrict__ T1,
                                               const ushort_t* __restrict__ T2,
                                               const ushort_t* __restrict__ T3,
                                               const ushort_t* __restrict__ T4,
                                               const ushort_t* __restrict__ T5,
                                               const ushort_t* __restrict__ Wfrag,
                                               const float* __restrict__ bias,
                                               float* __restrict__ out) {
    const int wave = threadIdx.x >> 6, lane = threadIdx.x & 63;
    const int quad = lane >> 4, col = lane & 15;
    const int tb = blockIdx.x * 128 + wave * 32;      // 2 tiles: tb, tb+16
    const int r0 = tb + col, r1 = tb + 16 + col;
    const ushort_t* Tbuf[6] = {X0, T1, T2, T3, T4, T5};

    frag_cd acc0[4], acc1[4];
#pragma unroll
    for (int ct = 0; ct < 4; ++ct) {
        acc0[ct] = (frag_cd){0.f, 0.f, 0.f, 0.f};
        acc1[ct] = (frag_cd){0.f, 0.f, 0.f, 0.f};
    }

#pragma unroll
    for (int s = 0; s < 12; ++s) {
        const int f0 = (s & 1) * 32 + quad * 8;
        frag_ab fa0 = *(const frag_ab*)(Tbuf[s >> 1] + (size_t)r0 * F_ + f0);
        frag_ab fa1 = *(const frag_ab*)(Tbuf[s >> 1] + (size_t)r1 * F_ + f0);
#pragma unroll
        for (int ct = 0; ct < 4; ++ct) {
            frag_ab bfr = *(const frag_ab*)(Wfrag + (((s * 4 + ct) * 64 + lane) << 3));
            acc0[ct] = __builtin_amdgcn_mfma_f32_16x16x32_bf16(fa0, bfr, acc0[ct], 0, 0, 0);
            acc1[ct] = __builtin_amdgcn_mfma_f32_16x16x32_bf16(fa1, bfr, acc1[ct], 0, 0, 0);
        }
    }

    // C/D: col = lane&15, row = quad*4 + reg
#pragma unroll
    for (int ct = 0; ct < 4; ++ct) {
        const int o = ct * 16 + col;
        const float bv = bias[o];
#pragma unroll
        for (int reg = 0; reg < 4; ++reg) {
            int ra = tb + quad * 4 + reg;
            int rb = ra + 16;
            out[(size_t)(ra & 7) * N_V * OUT_ + (size_t)(ra >> 3) * OUT_ + o] = acc0[ct][reg] + bv;
            out[(size_t)(rb & 7) * N_V * OUT_ + (size_t)(rb >> 3) * OUT_ + o] = acc1[ct][reg] + bv;
        }
    }
}

// ---------------- launcher ----------------

extern "C" void kernel_launch(void* const* d_in, const int* in_sizes, int n_in,
                              void* d_out, int out_size, void* d_ws, size_t ws_size,
                              hipStream_t stream) {
    const float* x    = (const float*)d_in[0];
    const int*   rows = (const int*)  d_in[1];
    const int*   cols = (const int*)  d_in[2];
    const float* vals = (const float*)d_in[3];
    const float* W    = (const float*)d_in[4];
    const float* bias = (const float*)d_in[5];
    float* out = (float*)d_out;

    const size_t TSZ = (size_t)N_V * BF;           // bf16 elements per T buffer
    ushort_t* T1 = (ushort_t*)d_ws;
    ushort_t* T2 = T1 + TSZ;
    ushort_t* T3 = T2 + TSZ;
    ushort_t* T4 = T3 + TSZ;
    ushort_t* T5 = T4 + TSZ;
    ushort_t* X0 = T5 + TSZ;
    ushort_t* Wfrag = X0 + TSZ;                    // 24576 ushorts
    int*  cnt   = (int*)(Wfrag + 24576);           // NPAIR counters
    int2* edges = (int2*)(cnt + NPAIR + 64);       // NPAIR * PCAP int2

    prep_kernel<<<20136, 256, 0, stream>>>(x, (uint_t*)X0, W, Wfrag, cnt);
    scatter_kernel<<<(NNZ_ + 255) / 256, 256, 0, stream>>>(rows, cols, vals, cnt, edges);

    cheb_pair<false><<<CHEB_WAVES / 4, 256, 0, stream>>>(cnt, edges, X0, nullptr, T1);
    cheb_pair<true ><<<CHEB_WAVES / 4, 256, 0, stream>>>(cnt, edges, T1, X0, T2);
    cheb_pair<true ><<<CHEB_WAVES / 4, 256, 0, stream>>>(cnt, edges, T2, T1, T3);
    cheb_pair<true ><<<CHEB_WAVES / 4, 256, 0, stream>>>(cnt, edges, T3, T2, T4);
    cheb_pair<true ><<<CHEB_WAVES / 4, 256, 0, stream>>>(cnt, edges, T4, T3, T5);

    fc_mfma<<<(N_V * B_) / 128, 256, 0, stream>>>(X0, T1, T2, T3, T4, T5, Wfrag, bias, out);
}